// Round 11
// baseline (544.703 us; speedup 1.0000x reference)
//
#include <hip/hip_runtime.h>
#include <stdint.h>

typedef __attribute__((ext_vector_type(8))) short short8;
typedef __attribute__((ext_vector_type(4))) short short4v;
typedef __attribute__((ext_vector_type(4))) float floatx4;

__device__ __forceinline__ unsigned short f2bf(float x) {
  unsigned int u = __float_as_uint(x);
  u += 0x7fffu + ((u >> 16) & 1u);   // RNE
  return (unsigned short)(u >> 16);
}
__device__ __forceinline__ float bf2f(unsigned short b) {
  return __uint_as_float(((unsigned int)b) << 16);
}
__device__ __forceinline__ int sw3(int r) { return (r & 7) ^ (((r >> 3) & 1) * 3); }

// ---- unified prologue: weight frags + h bf16 table (layouts as R7) ----
__global__ void prep_kernel(const float* __restrict__ h, const float* __restrict__ W1,
                            const float* __restrict__ W2, const float* __restrict__ W3,
                            unsigned short* __restrict__ HBF, unsigned short* __restrict__ W1F,
                            unsigned short* __restrict__ W2F, unsigned short* __restrict__ W3F,
                            int nh4) {
  const int t = threadIdx.x;
  int b = blockIdx.x;
  if (b < 512) {
    int u = b * 256 + t;
    int j = u & 7, kq = (u >> 3) & 3, n = (u >> 5) & 255, k32 = u >> 13;
    W1F[u] = f2bf(W1[(k32 * 32 + kq * 8 + j) * 256 + n]);
    return;
  }
  b -= 512;
  if (b < 256) {
    int u = b * 256 + t;
    int j = u & 7, kq = (u >> 3) & 3, n = (u >> 5) & 255, k32 = u >> 13;
    W2F[u] = f2bf(W2[(k32 * 32 + kq * 8 + j) * 256 + n]);
    return;
  }
  b -= 256;
  if (b < 16) {
    int u = b * 256 + t;
    int j = u & 7, L = (u >> 3) & 63, k32 = u >> 9;
    int n = L & 15, kq = L >> 4;
    W3F[u] = (n < 2) ? f2bf(W3[(k32 * 32 + kq * 8 + j) * 2 + n]) : (unsigned short)0;
    return;
  }
  b -= 16;
  int u = b * 256 + t;
  if (u < nh4) {
    float4 v = ((const float4*)h)[u];
    short4v s;
    s[0] = (short)f2bf(v.x); s[1] = (short)f2bf(v.y);
    s[2] = (short)f2bf(v.z); s[3] = (short)f2bf(v.w);
    ((short4v*)HBF)[u] = s;
  }
}

// ---- main kernel: M=64, K-chunked A staging (K=128 chunks, dbuf) ----
// LDS: C[2] chunk buffers 64 rows x (256 B data + 16 B pad) = 2x17 KB; ioff 512 B
// -> ~35 KB -> 4 blocks/CU (16 waves, 4/SIMD). X/X2 (32 KB, R7 swizzle) overlay C.
// Per wave: M=64 x N=64 (acc 64 VGPR), B-ring depth 2 (32), gather half-batch
// g[2] (16 transient) -> peak ~126 VGPR, no spill at launch_bounds(256,4).
__global__ __launch_bounds__(256, 4)
void edge_mlp7(const unsigned short* __restrict__ hbf,
               const int* __restrict__ dst,
               const int* __restrict__ src,
               const unsigned short* __restrict__ W1F,
               const unsigned short* __restrict__ W2F,
               const unsigned short* __restrict__ W3F,
               float* __restrict__ out) {
  __shared__ unsigned short C[2][64 * 136];   // row stride 136 shorts = 272 B
  __shared__ int ioff[128];
  unsigned short* X = &C[0][0];               // [64][256] overlay after L1

  const int t = threadIdx.x, lane = t & 63, w = t >> 6;
  const int lq = lane >> 4, lm = lane & 15;
  const int m0 = blockIdx.x * 64;

  if (t < 64)       ioff[t] = dst[m0 + t];
  else if (t < 128) ioff[t] = src[m0 + t - 64];

  const short8* B1 = (const short8*)W1F;
  const short8* B2 = (const short8*)W2F;
  const short8* B3 = (const short8*)W3F;

  // unit u = it*256+t -> row r=u>>4 (wave-uniform groups of 4 rows), c16 cc=u&15;
  // each load instr = 4 contiguous 256 B segments. chunk kc: rows from dst (kc<2)
  // or src half; byte offset (kc&1)*256 within the 512 B node row.
  auto gload = [&](int kc, int it, short8* gp) {
    int u = it * 256 + t;
    int r = u >> 4, cc = u & 15;
    int node = ioff[(kc >= 2 ? 64 : 0) + r];
    *gp = ((const short8*)hbf)[(size_t)node * 32 + (kc & 1) * 16 + cc];
  };
  auto gwrite = [&](int buf, int it, const short8* gp) {
    int u = it * 256 + t;
    int r = u >> 4, cc = u & 15;
    *(short8*)&C[buf][r * 136 + cc * 8] = *gp;
  };

  __syncthreads();   // ioff visible
  // ---- stage chunk 0
  {
    short8 g[4];
#pragma unroll
    for (int it = 0; it < 4; ++it) gload(0, it, &g[it]);
#pragma unroll
    for (int it = 0; it < 4; ++it) gwrite(0, it, &g[it]);
  }

  floatx4 acc[4][4];
#pragma unroll
  for (int i = 0; i < 4; ++i)
#pragma unroll
    for (int j = 0; j < 4; ++j) acc[i][j] = (floatx4)(0.0f);

  // prime B1 ring (k32 = 0,1)
  short8 bq[2][4];
#pragma unroll
  for (int s = 0; s < 2; ++s)
#pragma unroll
    for (int jt = 0; jt < 4; ++jt)
      bq[s][jt] = B1[(s * 256 + w * 64 + jt * 16 + lm) * 4 + lq];
  __syncthreads();   // chunk 0 staged

  // ---- Layer 1: 4 chunks x 4 k-steps; gather(kc+1) in 2 half-batches
  for (int kc = 0; kc < 4; ++kc) {
    const unsigned short* Cc = C[kc & 1];
    const int nb = (kc + 1) & 1;
    const bool pre = kc < 3;
    short8 g[2];
    if (pre) { gload(kc + 1, 0, &g[0]); gload(kc + 1, 1, &g[1]); }
#pragma unroll
    for (int sl = 0; sl < 4; ++sl) {
      const int s = kc * 4 + sl;
#pragma unroll
      for (int i = 0; i < 4; ++i) {
        int r = i * 16 + lm;
        short8 af = *(const short8*)&Cc[r * 136 + (sl * 4 + lq) * 8];
#pragma unroll
        for (int j = 0; j < 4; ++j)
          acc[i][j] = __builtin_amdgcn_mfma_f32_16x16x32_bf16(af, bq[s & 1][j], acc[i][j], 0, 0, 0);
      }
      if (s < 14)
#pragma unroll
        for (int jt = 0; jt < 4; ++jt)
          bq[s & 1][jt] = B1[((s + 2) * 256 + w * 64 + jt * 16 + lm) * 4 + lq];
      if (sl == 1 && pre) {
        gwrite(nb, 0, &g[0]); gwrite(nb, 1, &g[1]);
        gload(kc + 1, 2, &g[0]); gload(kc + 1, 3, &g[1]);
      }
    }
    if (pre) { gwrite(nb, 2, &g[0]); gwrite(nb, 3, &g[1]); }
    __syncthreads();
  }

  // ---- Epilogue 1: relu -> X (C/D: col=lane&15, row=quad*4+reg)
#pragma unroll
  for (int i = 0; i < 4; ++i) {
    int row0 = i * 16 + lq * 4;
#pragma unroll
    for (int j = 0; j < 4; ++j) {
      int col = w * 64 + j * 16 + lm, c8 = col >> 3, ce = col & 7;
#pragma unroll
      for (int rg = 0; rg < 4; ++rg) {
        int row = row0 + rg;
        float v = acc[i][j][rg];
        v = v > 0.0f ? v : 0.0f;
        X[row * 256 + (((c8 ^ sw3(row)) << 3) | ce)] = f2bf(v);
      }
    }
  }
#pragma unroll
  for (int i = 0; i < 4; ++i)
#pragma unroll
    for (int j = 0; j < 4; ++j) acc[i][j] = (floatx4)(0.0f);
  __syncthreads();   // X visible

  // ---- Layer 2: K=256, 8 k-steps, B-ring depth 2
#pragma unroll
  for (int s = 0; s < 2; ++s)
#pragma unroll
    for (int jt = 0; jt < 4; ++jt)
      bq[s][jt] = B2[(s * 256 + w * 64 + jt * 16 + lm) * 4 + lq];
#pragma unroll
  for (int s = 0; s < 8; ++s) {
#pragma unroll
    for (int i = 0; i < 4; ++i) {
      int r = i * 16 + lm, cch = s * 4 + lq;
      short8 af = *(const short8*)&X[r * 256 + ((cch ^ sw3(r)) << 3)];
#pragma unroll
      for (int j = 0; j < 4; ++j)
        acc[i][j] = __builtin_amdgcn_mfma_f32_16x16x32_bf16(af, bq[s & 1][j], acc[i][j], 0, 0, 0);
    }
    if (s < 6)
#pragma unroll
      for (int jt = 0; jt < 4; ++jt)
        bq[s & 1][jt] = B2[((s + 2) * 256 + w * 64 + jt * 16 + lm) * 4 + lq];
  }
  __syncthreads();   // all X reads done

  // ---- Epilogue 2: relu -> X in place
#pragma unroll
  for (int i = 0; i < 4; ++i) {
    int row0 = i * 16 + lq * 4;
#pragma unroll
    for (int j = 0; j < 4; ++j) {
      int col = w * 64 + j * 16 + lm, c8 = col >> 3, ce = col & 7;
#pragma unroll
      for (int rg = 0; rg < 4; ++rg) {
        int row = row0 + rg;
        float v = acc[i][j][rg];
        v = v > 0.0f ? v : 0.0f;
        X[row * 256 + (((c8 ^ sw3(row)) << 3) | ce)] = f2bf(v);
      }
    }
  }
  __syncthreads();

  // ---- Layer 3: X @ W3 via MFMA (N padded to 16; cols 0,1 valid)
  {
    floatx4 a3 = (floatx4)(0.0f);
#pragma unroll
    for (int s = 0; s < 8; ++s) {
      short8 b3 = B3[s * 64 + lane];
      int r = w * 16 + lm;
      short8 af = *(const short8*)&X[r * 256 + (((s * 4 + lq) ^ sw3(r)) << 3)];
      a3 = __builtin_amdgcn_mfma_f32_16x16x32_bf16(af, b3, a3, 0, 0, 0);
    }
    if (lm < 2) {
#pragma unroll
      for (int rg = 0; rg < 4; ++rg)
        out[(m0 + w * 16 + lq * 4 + rg) * 2 + lm] = a3[rg];
    }
  }
}

// ---- legacy weight-frag kernel (fallback path only) ----
__global__ void wfrag_kernel(const float* __restrict__ W,
                             unsigned short* __restrict__ out, int total) {
  int u = blockIdx.x * 256 + threadIdx.x;
  if (u >= total) return;
  int j = u & 7, kq = (u >> 3) & 3, n = (u >> 5) & 255, k32 = u >> 13;
  out[u] = f2bf(W[(k32 * 32 + kq * 8 + j) * 256 + n]);
}

// ---- fp32-gather fallback (tiny workspace) ----
__global__ __launch_bounds__(256, 2)
void edge_mlp_fb(const float* __restrict__ h,
                 const int* __restrict__ dst,
                 const int* __restrict__ src,
                 const unsigned short* __restrict__ W1F,
                 const unsigned short* __restrict__ W2F,
                 const float* __restrict__ W3,
                 float* __restrict__ out) {
  __shared__ unsigned short A[64 * 512];
  __shared__ float w3s[512];
  __shared__ int ioff[128];
  unsigned short* X = A;
  const int t = threadIdx.x, lane = t & 63, w = t >> 6;
  const int lq = lane >> 4, lm = lane & 15;
  const int m0 = blockIdx.x * 64;
  if (t < 64) ioff[t] = dst[m0 + t];
  else if (t < 128) ioff[t] = src[m0 + t - 64];
  w3s[t] = W3[t];
  w3s[t + 256] = W3[t + 256];
  __syncthreads();
  {
    const int c = lane, half = (c >= 32) ? 64 : 0, cc = c & 31;
#pragma unroll
    for (int it = 0; it < 16; ++it) {
      int r = it * 4 + w;
      int node = ioff[half + r];
      const float4* h4 = (const float4*)h;
      float4 v0 = h4[node * 64 + cc * 2], v1 = h4[node * 64 + cc * 2 + 1];
      short8 v;
      v[0] = (short)f2bf(v0.x); v[1] = (short)f2bf(v0.y);
      v[2] = (short)f2bf(v0.z); v[3] = (short)f2bf(v0.w);
      v[4] = (short)f2bf(v1.x); v[5] = (short)f2bf(v1.y);
      v[6] = (short)f2bf(v1.z); v[7] = (short)f2bf(v1.w);
      *(short8*)&A[r * 512 + ((c ^ (r & 7)) << 3)] = v;
    }
  }
  floatx4 acc[4][4];
#pragma unroll
  for (int i = 0; i < 4; ++i)
#pragma unroll
    for (int j = 0; j < 4; ++j) acc[i][j] = (floatx4)(0.0f);
  __syncthreads();
  const short8* B1 = (const short8*)W1F;
  const short8* B2 = (const short8*)W2F;
#pragma unroll
  for (int k32 = 0; k32 < 16; ++k32) {
    short8 b[4], af[4];
#pragma unroll
    for (int jt = 0; jt < 4; ++jt)
      b[jt] = B1[(k32 * 256 + w * 64 + jt * 16 + lm) * 4 + lq];
#pragma unroll
    for (int i = 0; i < 4; ++i) {
      int r = i * 16 + lm, c = k32 * 4 + lq;
      af[i] = *(const short8*)&A[r * 512 + ((c ^ (r & 7)) << 3)];
    }
#pragma unroll
    for (int i = 0; i < 4; ++i)
#pragma unroll
      for (int j = 0; j < 4; ++j)
        acc[i][j] = __builtin_amdgcn_mfma_f32_16x16x32_bf16(af[i], b[j], acc[i][j], 0, 0, 0);
  }
  __syncthreads();
#pragma unroll
  for (int i = 0; i < 4; ++i) {
    int row0 = i * 16 + lq * 4;
#pragma unroll
    for (int j = 0; j < 4; ++j) {
      int col = w * 64 + j * 16 + lm, c8 = col >> 3, ce = col & 7;
#pragma unroll
      for (int rg = 0; rg < 4; ++rg) {
        int row = row0 + rg;
        float v = acc[i][j][rg];
        v = v > 0.0f ? v : 0.0f;
        X[row * 256 + (((c8 ^ (row & 7)) << 3) | ce)] = f2bf(v);
      }
    }
  }
#pragma unroll
  for (int i = 0; i < 4; ++i)
#pragma unroll
    for (int j = 0; j < 4; ++j) acc[i][j] = (floatx4)(0.0f);
  __syncthreads();
#pragma unroll
  for (int k32 = 0; k32 < 8; ++k32) {
    short8 b[4], af[4];
#pragma unroll
    for (int jt = 0; jt < 4; ++jt)
      b[jt] = B2[(k32 * 256 + w * 64 + jt * 16 + lm) * 4 + lq];
#pragma unroll
    for (int i = 0; i < 4; ++i) {
      int r = i * 16 + lm, c = k32 * 4 + lq;
      af[i] = *(const short8*)&X[r * 256 + ((c ^ (r & 7)) << 3)];
    }
#pragma unroll
    for (int i = 0; i < 4; ++i)
#pragma unroll
      for (int j = 0; j < 4; ++j)
        acc[i][j] = __builtin_amdgcn_mfma_f32_16x16x32_bf16(af[i], b[j], acc[i][j], 0, 0, 0);
  }
  __syncthreads();
#pragma unroll
  for (int i = 0; i < 4; ++i) {
    int row0 = i * 16 + lq * 4;
#pragma unroll
    for (int j = 0; j < 4; ++j) {
      int col = w * 64 + j * 16 + lm, c8 = col >> 3, ce = col & 7;
#pragma unroll
      for (int rg = 0; rg < 4; ++rg) {
        int row = row0 + rg;
        float v = acc[i][j][rg];
        v = v > 0.0f ? v : 0.0f;
        X[row * 256 + (((c8 ^ (row & 7)) << 3) | ce)] = f2bf(v);
      }
    }
  }
  __syncthreads();
  {
    int r = t >> 2, o = (t >> 1) & 1, hh = t & 1;
    float s = 0.0f;
#pragma unroll
    for (int it = 0; it < 16; ++it) {
      int c = hh * 16 + it;
      short8 xv = *(const short8*)&X[r * 256 + ((c ^ (r & 7)) << 3)];
#pragma unroll
      for (int e = 0; e < 8; ++e)
        s += bf2f((unsigned short)xv[e]) * w3s[((c << 3) + e) * 2 + o];
    }
    s += __shfl_xor(s, 1);
    if (hh == 0) out[(m0 + r) * 2 + o] = s;
  }
}

extern "C" void kernel_launch(void* const* d_in, const int* in_sizes, int n_in,
                              void* d_out, int out_size, void* d_ws, size_t ws_size,
                              hipStream_t stream) {
  const float* h   = (const float*)d_in[0];
  const int*   dst = (const int*)d_in[1];
  const int*   src = (const int*)d_in[2];
  const float* W1  = (const float*)d_in[3];
  const float* W2  = (const float*)d_in[4];
  const float* W3  = (const float*)d_in[5];
  float* out = (float*)d_out;

  const int h_elems = in_sizes[0];
  const int n_pairs = in_sizes[1];

  const size_t hbf_elems = (size_t)h_elems;
  const bool use_hbf =
      ws_size >= (hbf_elems + 131072 + 65536 + 4096) * sizeof(unsigned short);

  unsigned short* HBF = (unsigned short*)d_ws;
  unsigned short* W1F = HBF + hbf_elems;
  unsigned short* W2F = W1F + 131072;
  unsigned short* W3F = W2F + 65536;

  if (use_hbf) {
    int nh4 = h_elems / 4;
    int grid = 512 + 256 + 16 + (nh4 + 255) / 256;
    prep_kernel<<<grid, 256, 0, stream>>>(h, W1, W2, W3, HBF, W1F, W2F, W3F, nh4);
    edge_mlp7<<<n_pairs / 64, 256, 0, stream>>>(HBF, dst, src, W1F, W2F, W3F, out);
  } else {
    unsigned short* W1Fb = (unsigned short*)d_ws;
    unsigned short* W2Fb = W1Fb + 131072;
    wfrag_kernel<<<512, 256, 0, stream>>>(W1, W1Fb, 131072);
    wfrag_kernel<<<256, 256, 0, stream>>>(W2, W2Fb, 65536);
    edge_mlp_fb<<<n_pairs / 64, 256, 0, stream>>>(h, dst, src, W1Fb, W2Fb, W3, out);
  }
}

// Round 12
// 456.770 us; speedup vs baseline: 1.1925x; 1.1925x over previous
//
#include <hip/hip_runtime.h>
#include <stdint.h>

typedef __attribute__((ext_vector_type(8))) short short8;
typedef __attribute__((ext_vector_type(4))) short short4v;
typedef __attribute__((ext_vector_type(4))) float floatx4;

__device__ __forceinline__ unsigned short f2bf(float x) {
  unsigned int u = __float_as_uint(x);
  u += 0x7fffu + ((u >> 16) & 1u);   // RNE
  return (unsigned short)(u >> 16);
}
__device__ __forceinline__ float bf2f(unsigned short b) {
  return __uint_as_float(((unsigned int)b) << 16);
}
__device__ __forceinline__ int sw3(int r) { return (r & 7) ^ (((r >> 3) & 1) * 3); }

// ---- unified prologue: weight frags + h bf16 table (layouts as R7) ----
__global__ void prep_kernel(const float* __restrict__ h, const float* __restrict__ W1,
                            const float* __restrict__ W2, const float* __restrict__ W3,
                            unsigned short* __restrict__ HBF, unsigned short* __restrict__ W1F,
                            unsigned short* __restrict__ W2F, unsigned short* __restrict__ W3F,
                            int nh4) {
  const int t = threadIdx.x;
  int b = blockIdx.x;
  if (b < 512) {
    int u = b * 256 + t;
    int j = u & 7, kq = (u >> 3) & 3, n = (u >> 5) & 255, k32 = u >> 13;
    W1F[u] = f2bf(W1[(k32 * 32 + kq * 8 + j) * 256 + n]);
    return;
  }
  b -= 512;
  if (b < 256) {
    int u = b * 256 + t;
    int j = u & 7, kq = (u >> 3) & 3, n = (u >> 5) & 255, k32 = u >> 13;
    W2F[u] = f2bf(W2[(k32 * 32 + kq * 8 + j) * 256 + n]);
    return;
  }
  b -= 256;
  if (b < 16) {
    int u = b * 256 + t;
    int j = u & 7, L = (u >> 3) & 63, k32 = u >> 9;
    int n = L & 15, kq = L >> 4;
    W3F[u] = (n < 2) ? f2bf(W3[(k32 * 32 + kq * 8 + j) * 2 + n]) : (unsigned short)0;
    return;
  }
  b -= 16;
  int u = b * 256 + t;
  if (u < nh4) {
    float4 v = ((const float4*)h)[u];
    short4v s;
    s[0] = (short)f2bf(v.x); s[1] = (short)f2bf(v.y);
    s[2] = (short)f2bf(v.z); s[3] = (short)f2bf(v.w);
    ((short4v*)HBF)[u] = s;
  }
}

// ---- main kernel: M=64, K-chunked A staging (K=128 chunks, dbuf) ----
// LDS: C[2] chunk buffers 64 rows x (256 B + 16 B pad) = 2x17 KB; ioff 512 B
// -> ~35 KB. launch_bounds(256,3): VGPR budget 168 so the allocator does NOT
// drop to the 64 tier (R11 failure); live set ~125 -> expect 128 alloc ->
// HW fits 4 blocks/CU (LDS 140 KB, VGPR 4x128). X (R7 swizzle) overlays C.
__global__ __launch_bounds__(256, 3)
void edge_mlp7(const unsigned short* __restrict__ hbf,
               const int* __restrict__ dst,
               const int* __restrict__ src,
               const unsigned short* __restrict__ W1F,
               const unsigned short* __restrict__ W2F,
               const unsigned short* __restrict__ W3F,
               float* __restrict__ out) {
  __shared__ unsigned short C[2][64 * 136];   // row stride 136 shorts = 272 B
  __shared__ int ioff[128];
  unsigned short* X = &C[0][0];               // [64][256] overlay after L1

  const int t = threadIdx.x, lane = t & 63, w = t >> 6;
  const int lq = lane >> 4, lm = lane & 15;
  const int m0 = blockIdx.x * 64;

  if (t < 64)       ioff[t] = dst[m0 + t];
  else if (t < 128) ioff[t] = src[m0 + t - 64];

  const short8* B1 = (const short8*)W1F;
  const short8* B2 = (const short8*)W2F;
  const short8* B3 = (const short8*)W3F;

  // unit u = it*256+t -> row r=u>>4 (wave-uniform groups of 4 rows), chunk cc=u&15;
  // each load instr = 4 contiguous 256 B segments. chunk kc: dst half (kc<2) or
  // src half; byte offset (kc&1)*256 within the 512 B node row.
  auto gload = [&](int kc, int it, short8* gp) {
    int u = it * 256 + t;
    int r = u >> 4, cc = u & 15;
    int node = ioff[(kc >= 2 ? 64 : 0) + r];
    *gp = ((const short8*)hbf)[(size_t)node * 32 + (kc & 1) * 16 + cc];
  };
  auto gwrite = [&](int buf, int it, const short8* gp) {
    int u = it * 256 + t;
    int r = u >> 4, cc = u & 15;
    *(short8*)&C[buf][r * 136 + cc * 8] = *gp;
  };

  __syncthreads();   // ioff visible
  // ---- stage chunk 0
  {
    short8 g[4];
#pragma unroll
    for (int it = 0; it < 4; ++it) gload(0, it, &g[it]);
#pragma unroll
    for (int it = 0; it < 4; ++it) gwrite(0, it, &g[it]);
  }

  floatx4 acc[4][4];
#pragma unroll
  for (int i = 0; i < 4; ++i)
#pragma unroll
    for (int j = 0; j < 4; ++j) acc[i][j] = (floatx4)(0.0f);

  // prime B1 ring (k32 = 0,1)
  short8 bq[2][4];
#pragma unroll
  for (int s = 0; s < 2; ++s)
#pragma unroll
    for (int jt = 0; jt < 4; ++jt)
      bq[s][jt] = B1[(s * 256 + w * 64 + jt * 16 + lm) * 4 + lq];
  __syncthreads();   // chunk 0 staged

  // ---- Layer 1: 4 chunks x 4 k-steps; gather(kc+1) in 2 half-batches
  for (int kc = 0; kc < 4; ++kc) {
    const unsigned short* Cc = C[kc & 1];
    const int nb = (kc + 1) & 1;
    const bool pre = kc < 3;
    short8 g[2];
    if (pre) { gload(kc + 1, 0, &g[0]); gload(kc + 1, 1, &g[1]); }
#pragma unroll
    for (int sl = 0; sl < 4; ++sl) {
      const int s = kc * 4 + sl;
#pragma unroll
      for (int i = 0; i < 4; ++i) {
        int r = i * 16 + lm;
        short8 af = *(const short8*)&Cc[r * 136 + (sl * 4 + lq) * 8];
#pragma unroll
        for (int j = 0; j < 4; ++j)
          acc[i][j] = __builtin_amdgcn_mfma_f32_16x16x32_bf16(af, bq[s & 1][j], acc[i][j], 0, 0, 0);
      }
      if (s < 14)
#pragma unroll
        for (int jt = 0; jt < 4; ++jt)
          bq[s & 1][jt] = B1[((s + 2) * 256 + w * 64 + jt * 16 + lm) * 4 + lq];
      if (sl == 1 && pre) {
        gwrite(nb, 0, &g[0]); gwrite(nb, 1, &g[1]);
        gload(kc + 1, 2, &g[0]); gload(kc + 1, 3, &g[1]);
      }
    }
    if (pre) { gwrite(nb, 2, &g[0]); gwrite(nb, 3, &g[1]); }
    __syncthreads();
  }

  // ---- Epilogue 1: relu -> X (C/D: col=lane&15, row=quad*4+reg)
#pragma unroll
  for (int i = 0; i < 4; ++i) {
    int row0 = i * 16 + lq * 4;
#pragma unroll
    for (int j = 0; j < 4; ++j) {
      int col = w * 64 + j * 16 + lm, c8 = col >> 3, ce = col & 7;
#pragma unroll
      for (int rg = 0; rg < 4; ++rg) {
        int row = row0 + rg;
        float v = acc[i][j][rg];
        v = v > 0.0f ? v : 0.0f;
        X[row * 256 + (((c8 ^ sw3(row)) << 3) | ce)] = f2bf(v);
      }
    }
  }
#pragma unroll
  for (int i = 0; i < 4; ++i)
#pragma unroll
    for (int j = 0; j < 4; ++j) acc[i][j] = (floatx4)(0.0f);
  __syncthreads();   // X visible

  // ---- Layer 2: K=256, 8 k-steps, B-ring depth 2
#pragma unroll
  for (int s = 0; s < 2; ++s)
#pragma unroll
    for (int jt = 0; jt < 4; ++jt)
      bq[s][jt] = B2[(s * 256 + w * 64 + jt * 16 + lm) * 4 + lq];
#pragma unroll
  for (int s = 0; s < 8; ++s) {
#pragma unroll
    for (int i = 0; i < 4; ++i) {
      int r = i * 16 + lm, cch = s * 4 + lq;
      short8 af = *(const short8*)&X[r * 256 + ((cch ^ sw3(r)) << 3)];
#pragma unroll
      for (int j = 0; j < 4; ++j)
        acc[i][j] = __builtin_amdgcn_mfma_f32_16x16x32_bf16(af, bq[s & 1][j], acc[i][j], 0, 0, 0);
    }
    if (s < 6)
#pragma unroll
      for (int jt = 0; jt < 4; ++jt)
        bq[s & 1][jt] = B2[((s + 2) * 256 + w * 64 + jt * 16 + lm) * 4 + lq];
  }
  __syncthreads();   // all X reads done

  // ---- Epilogue 2: relu -> X in place
#pragma unroll
  for (int i = 0; i < 4; ++i) {
    int row0 = i * 16 + lq * 4;
#pragma unroll
    for (int j = 0; j < 4; ++j) {
      int col = w * 64 + j * 16 + lm, c8 = col >> 3, ce = col & 7;
#pragma unroll
      for (int rg = 0; rg < 4; ++rg) {
        int row = row0 + rg;
        float v = acc[i][j][rg];
        v = v > 0.0f ? v : 0.0f;
        X[row * 256 + (((c8 ^ sw3(row)) << 3) | ce)] = f2bf(v);
      }
    }
  }
  __syncthreads();

  // ---- Layer 3: X @ W3 via MFMA (N padded to 16; cols 0,1 valid)
  {
    floatx4 a3 = (floatx4)(0.0f);
#pragma unroll
    for (int s = 0; s < 8; ++s) {
      short8 b3 = B3[s * 64 + lane];
      int r = w * 16 + lm;
      short8 af = *(const short8*)&X[r * 256 + (((s * 4 + lq) ^ sw3(r)) << 3)];
      a3 = __builtin_amdgcn_mfma_f32_16x16x32_bf16(af, b3, a3, 0, 0, 0);
    }
    if (lm < 2) {
#pragma unroll
      for (int rg = 0; rg < 4; ++rg)
        out[(m0 + w * 16 + lq * 4 + rg) * 2 + lm] = a3[rg];
    }
  }
}

// ---- legacy weight-frag kernel (fallback path only) ----
__global__ void wfrag_kernel(const float* __restrict__ W,
                             unsigned short* __restrict__ out, int total) {
  int u = blockIdx.x * 256 + threadIdx.x;
  if (u >= total) return;
  int j = u & 7, kq = (u >> 3) & 3, n = (u >> 5) & 255, k32 = u >> 13;
  out[u] = f2bf(W[(k32 * 32 + kq * 8 + j) * 256 + n]);
}

// ---- fp32-gather fallback (tiny workspace) ----
__global__ __launch_bounds__(256, 2)
void edge_mlp_fb(const float* __restrict__ h,
                 const int* __restrict__ dst,
                 const int* __restrict__ src,
                 const unsigned short* __restrict__ W1F,
                 const unsigned short* __restrict__ W2F,
                 const float* __restrict__ W3,
                 float* __restrict__ out) {
  __shared__ unsigned short A[64 * 512];
  __shared__ float w3s[512];
  __shared__ int ioff[128];
  unsigned short* X = A;
  const int t = threadIdx.x, lane = t & 63, w = t >> 6;
  const int lq = lane >> 4, lm = lane & 15;
  const int m0 = blockIdx.x * 64;
  if (t < 64) ioff[t] = dst[m0 + t];
  else if (t < 128) ioff[t] = src[m0 + t - 64];
  w3s[t] = W3[t];
  w3s[t + 256] = W3[t + 256];
  __syncthreads();
  {
    const int c = lane, half = (c >= 32) ? 64 : 0, cc = c & 31;
#pragma unroll
    for (int it = 0; it < 16; ++it) {
      int r = it * 4 + w;
      int node = ioff[half + r];
      const float4* h4 = (const float4*)h;
      float4 v0 = h4[node * 64 + cc * 2], v1 = h4[node * 64 + cc * 2 + 1];
      short8 v;
      v[0] = (short)f2bf(v0.x); v[1] = (short)f2bf(v0.y);
      v[2] = (short)f2bf(v0.z); v[3] = (short)f2bf(v0.w);
      v[4] = (short)f2bf(v1.x); v[5] = (short)f2bf(v1.y);
      v[6] = (short)f2bf(v1.z); v[7] = (short)f2bf(v1.w);
      *(short8*)&A[r * 512 + ((c ^ (r & 7)) << 3)] = v;
    }
  }
  floatx4 acc[4][4];
#pragma unroll
  for (int i = 0; i < 4; ++i)
#pragma unroll
    for (int j = 0; j < 4; ++j) acc[i][j] = (floatx4)(0.0f);
  __syncthreads();
  const short8* B1 = (const short8*)W1F;
  const short8* B2 = (const short8*)W2F;
#pragma unroll
  for (int k32 = 0; k32 < 16; ++k32) {
    short8 b[4], af[4];
#pragma unroll
    for (int jt = 0; jt < 4; ++jt)
      b[jt] = B1[(k32 * 256 + w * 64 + jt * 16 + lm) * 4 + lq];
#pragma unroll
    for (int i = 0; i < 4; ++i) {
      int r = i * 16 + lm, c = k32 * 4 + lq;
      af[i] = *(const short8*)&A[r * 512 + ((c ^ (r & 7)) << 3)];
    }
#pragma unroll
    for (int i = 0; i < 4; ++i)
#pragma unroll
      for (int j = 0; j < 4; ++j)
        acc[i][j] = __builtin_amdgcn_mfma_f32_16x16x32_bf16(af[i], b[j], acc[i][j], 0, 0, 0);
  }
  __syncthreads();
#pragma unroll
  for (int i = 0; i < 4; ++i) {
    int row0 = i * 16 + lq * 4;
#pragma unroll
    for (int j = 0; j < 4; ++j) {
      int col = w * 64 + j * 16 + lm, c8 = col >> 3, ce = col & 7;
#pragma unroll
      for (int rg = 0; rg < 4; ++rg) {
        int row = row0 + rg;
        float v = acc[i][j][rg];
        v = v > 0.0f ? v : 0.0f;
        X[row * 256 + (((c8 ^ (row & 7)) << 3) | ce)] = f2bf(v);
      }
    }
  }
#pragma unroll
  for (int i = 0; i < 4; ++i)
#pragma unroll
    for (int j = 0; j < 4; ++j) acc[i][j] = (floatx4)(0.0f);
  __syncthreads();
#pragma unroll
  for (int k32 = 0; k32 < 8; ++k32) {
    short8 b[4], af[4];
#pragma unroll
    for (int jt = 0; jt < 4; ++jt)
      b[jt] = B2[(k32 * 256 + w * 64 + jt * 16 + lm) * 4 + lq];
#pragma unroll
    for (int i = 0; i < 4; ++i) {
      int r = i * 16 + lm, c = k32 * 4 + lq;
      af[i] = *(const short8*)&X[r * 256 + ((c ^ (r & 7)) << 3)];
    }
#pragma unroll
    for (int i = 0; i < 4; ++i)
#pragma unroll
      for (int j = 0; j < 4; ++j)
        acc[i][j] = __builtin_amdgcn_mfma_f32_16x16x32_bf16(af[i], b[j], acc[i][j], 0, 0, 0);
  }
  __syncthreads();
#pragma unroll
  for (int i = 0; i < 4; ++i) {
    int row0 = i * 16 + lq * 4;
#pragma unroll
    for (int j = 0; j < 4; ++j) {
      int col = w * 64 + j * 16 + lm, c8 = col >> 3, ce = col & 7;
#pragma unroll
      for (int rg = 0; rg < 4; ++rg) {
        int row = row0 + rg;
        float v = acc[i][j][rg];
        v = v > 0.0f ? v : 0.0f;
        X[row * 256 + (((c8 ^ (row & 7)) << 3) | ce)] = f2bf(v);
      }
    }
  }
  __syncthreads();
  {
    int r = t >> 2, o = (t >> 1) & 1, hh = t & 1;
    float s = 0.0f;
#pragma unroll
    for (int it = 0; it < 16; ++it) {
      int c = hh * 16 + it;
      short8 xv = *(const short8*)&X[r * 256 + ((c ^ (r & 7)) << 3)];
#pragma unroll
      for (int e = 0; e < 8; ++e)
        s += bf2f((unsigned short)xv[e]) * w3s[((c << 3) + e) * 2 + o];
    }
    s += __shfl_xor(s, 1);
    if (hh == 0) out[(m0 + r) * 2 + o] = s;
  }
}

extern "C" void kernel_launch(void* const* d_in, const int* in_sizes, int n_in,
                              void* d_out, int out_size, void* d_ws, size_t ws_size,
                              hipStream_t stream) {
  const float* h   = (const float*)d_in[0];
  const int*   dst = (const int*)d_in[1];
  const int*   src = (const int*)d_in[2];
  const float* W1  = (const float*)d_in[3];
  const float* W2  = (const float*)d_in[4];
  const float* W3  = (const float*)d_in[5];
  float* out = (float*)d_out;

  const int h_elems = in_sizes[0];
  const int n_pairs = in_sizes[1];

  const size_t hbf_elems = (size_t)h_elems;
  const bool use_hbf =
      ws_size >= (hbf_elems + 131072 + 65536 + 4096) * sizeof(unsigned short);

  unsigned short* HBF = (unsigned short*)d_ws;
  unsigned short* W1F = HBF + hbf_elems;
  unsigned short* W2F = W1F + 131072;
  unsigned short* W3F = W2F + 65536;

  if (use_hbf) {
    int nh4 = h_elems / 4;
    int grid = 512 + 256 + 16 + (nh4 + 255) / 256;
    prep_kernel<<<grid, 256, 0, stream>>>(h, W1, W2, W3, HBF, W1F, W2F, W3F, nh4);
    edge_mlp7<<<n_pairs / 64, 256, 0, stream>>>(HBF, dst, src, W1F, W2F, W3F, out);
  } else {
    unsigned short* W1Fb = (unsigned short*)d_ws;
    unsigned short* W2Fb = W1Fb + 131072;
    wfrag_kernel<<<512, 256, 0, stream>>>(W1, W1Fb, 131072);
    wfrag_kernel<<<256, 256, 0, stream>>>(W2, W2Fb, 65536);
    edge_mlp_fb<<<n_pairs / 64, 256, 0, stream>>>(h, dst, src, W1Fb, W2Fb, W3, out);
  }
}